// Round 7
// baseline (1132.464 us; speedup 1.0000x reference)
//
#include <hip/hip_runtime.h>
#include <cstdint>

#define TT  1024
#define BB  32
#define HH  8
#define DD  32
#define YDN 97
#define INN 256
#define NBH (BB*HH)

typedef float v2f __attribute__((ext_vector_type(2)));
typedef float v4f __attribute__((ext_vector_type(4)));

// packed fp32 FMA (v_pk_fma_f32 on CDNA)
#define PK(acc, a, b) (acc) = __builtin_elementwise_fma((a), (b), (acc))

template<int C>
__device__ __forceinline__ float dppf(float x) {
    return __int_as_float(__builtin_amdgcn_update_dpp(
        0, __float_as_int(x), C, 0xF, 0xF, true));
}
__device__ __forceinline__ float swz16(float x) {
    return __int_as_float(__builtin_amdgcn_ds_swizzle(__float_as_int(x), 0x401F));
}
__device__ __forceinline__ float red_max32(float v) {
    v = fmaxf(v, dppf<0xB1>(v));
    v = fmaxf(v, dppf<0x4E>(v));
    v = fmaxf(v, dppf<0x141>(v));
    v = fmaxf(v, dppf<0x140>(v));
    v = fmaxf(v, swz16(v));
    return v;
}
__device__ __forceinline__ float red_sum32(float v) {
    v += dppf<0xB1>(v);
    v += dppf<0x4E>(v);
    v += dppf<0x141>(v);
    v += dppf<0x140>(v);
    v += swz16(v);
    return v;
}
__device__ __forceinline__ float cexp(float v) {
    return __expf(fminf(v, 60.f));
}
__device__ __forceinline__ float sigm(float v) {
    return __builtin_amdgcn_rcpf(1.f + __expf(-v));
}
__device__ __forceinline__ float rdl(float v, int l) {
    return __int_as_float(__builtin_amdgcn_readlane(__float_as_int(v), l));
}

// ---------------------------------------------------------------------------
// Kernel 1: x = softmax(h) over last dim (rows of 32)
// ---------------------------------------------------------------------------
__global__ __launch_bounds__(256, 1) void softmax_x_kernel(
    const float* __restrict__ hg, float* __restrict__ xg)
{
    const int row  = blockIdx.x * 8 + (threadIdx.x >> 5);
    const int lane = threadIdx.x & 31;
    float v = hg[(size_t)row * DD + lane];
    float m = red_max32(v);
    float ex = __expf(v - m);
    float sm = red_sum32(ex);
    xg[(size_t)row * DD + lane] = ex * __builtin_amdgcn_rcpf(sm);
}

// ---------------------------------------------------------------------------
// Kernel 2: SRWM + fast-weight memory — ONE WAVE per (b,h). Zero barriers.
// Lane e owns columns: c1 = Wy[:,e]; c2 = Wy[:,64+e] (lanes 0-32) or
// wb[:,e-33] (lanes 33-36); c3 = Wq[:,e] (lanes 0-31) / Wk[:,e-32] (32-63);
// c4 = F[:,e] (lanes 0-31). Cross-lane traffic via a private in-wave LDS
// slab (write -> lgkmcnt -> read is safe in wave lockstep; deterministic).
// ---------------------------------------------------------------------------

#define LOADX(dst, t) {                                                       \
    int tc_ = (t); if (tc_ > TT-1) tc_ = TT-1;                                \
    const v4f* p_ = (const v4f*)(xg + ((size_t)tc_ * NBH + bh) * DD);         \
    _Pragma("unroll")                                                         \
    for (int g_ = 0; g_ < 8; g_++) {                                          \
        v4f v_ = p_[g_]; dst[2*g_] = v_.xy; dst[2*g_+1] = v_.zw;              \
    }                                                                         \
}

#define DOT32(res, X, C) {                                                    \
    v2f u0_={0.f,0.f},u1_={0.f,0.f},u2_={0.f,0.f},u3_={0.f,0.f};              \
    _Pragma("unroll")                                                         \
    for (int g_ = 0; g_ < 4; g_++) {                                          \
        PK(u0_, X[4*g_+0], C[4*g_+0]);                                        \
        PK(u1_, X[4*g_+1], C[4*g_+1]);                                        \
        PK(u2_, X[4*g_+2], C[4*g_+2]);                                        \
        PK(u3_, X[4*g_+3], C[4*g_+3]);                                        \
    }                                                                         \
    v2f t_ = (u0_ + u1_) + (u2_ + u3_);                                       \
    res = t_.x + t_.y;                                                        \
}

#define STEP(T, P, XC) {                                                      \
    /* ---- Phase A: three dots against current x ---- */                     \
    float pre1, pre2, pre3;                                                   \
    DOT32(pre1, XC, c1)                                                       \
    DOT32(pre2, XC, c2)                                                       \
    DOT32(pre3, XC, c3)                                                       \
    /* q/k softmax (halves of the wave), publish qmk and k-hat */             \
    float e3 = cexp(pre3);                                                    \
    float n3 = e3 * __builtin_amdgcn_rcpf(red_sum32(e3));                     \
    float o3 = __shfl_xor(n3, 32, 64);                                        \
    /* fq/fk softmax directly from pre1 (y[0:32] | y[32:64]) */               \
    float e1 = cexp(pre1);                                                    \
    float n1 = e1 * __builtin_amdgcn_rcpf(red_sum32(e1));                     \
    if (lo) { slab[P][0][half] = n3 - o3; slab[P][2][half] = n1; }            \
    else    { slab[P][1][half] = n3;      slab[P][3][half] = n1; }            \
    /* gates from pre2: lanes 33-36 hold beta0..3 preacts; lane 32 = fb */    \
    float sg2 = sigm(pre2);                                                   \
    float b0 = rdl(sg2, 33), b1 = rdl(sg2, 34);                               \
    float b2 = rdl(sg2, 35), b3 = rdl(sg2, 36);                               \
    float fb = rdl(sg2, 32);                                                  \
    float fv = pre2;                                                          \
    /* prefetch x(T+2) into XC (done with current value) */                   \
    LOADX(XC, (T) + 2)                                                        \
    /* ---- Phase B/C: qmk dots, rank-1 updates ---- */                       \
    const v4f* qm4 = (const v4f*)slab[P][0];                                  \
    const v4f* kh4 = (const v4f*)slab[P][1];                                  \
    v2f a1={0.f,0.f},a1b={0.f,0.f},a2={0.f,0.f},a2b={0.f,0.f};                \
    v2f a3={0.f,0.f},a3b={0.f,0.f};                                           \
    _Pragma("unroll")                                                         \
    for (int g = 0; g < 8; g++) {                                             \
        v4f q = qm4[g];                                                       \
        PK(a1,  q.xy, c1[2*g]); PK(a1b, q.zw, c1[2*g+1]);                     \
        PK(a2,  q.xy, c2[2*g]); PK(a2b, q.zw, c2[2*g+1]);                     \
        PK(a3,  q.xy, c3[2*g]); PK(a3b, q.zw, c3[2*g+1]);                     \
    }                                                                         \
    v2f t1 = a1 + a1b, t2 = a2 + a2b, t3 = a3 + a3b;                          \
    float bs1 = b0 * (t1.x + t1.y);                                           \
    float bs2 = (lane < 33 ? b0 : b3) * (t2.x + t2.y);                        \
    float bs3 = (lo ? b1 : b2) * (t3.x + t3.y);                               \
    v2f bs1v = {bs1, bs1}, bs2v = {bs2, bs2}, bs3v = {bs3, bs3};              \
    _Pragma("unroll")                                                         \
    for (int g = 0; g < 8; g++) {                                             \
        v4f kv = kh4[g];                                                      \
        PK(c1[2*g], bs1v, kv.xy); PK(c1[2*g+1], bs1v, kv.zw);                 \
        PK(c2[2*g], bs2v, kv.xy); PK(c2[2*g+1], bs2v, kv.zw);                 \
        PK(c3[2*g], bs3v, kv.xy); PK(c3[2*g+1], bs3v, kv.zw);                 \
    }                                                                         \
    /* ---- Phase D: delta-rule fast weights ---- */                          \
    const v4f* fq4 = (const v4f*)slab[P][2];                                  \
    const v4f* fk4 = (const v4f*)slab[P][3];                                  \
    v4f fkr[8];                                                               \
    _Pragma("unroll")                                                         \
    for (int g = 0; g < 8; g++) fkr[g] = fk4[g];                              \
    v2f v0={0.f,0.f}, v1={0.f,0.f};                                           \
    _Pragma("unroll")                                                         \
    for (int g = 0; g < 8; g++) {                                             \
        PK(v0, fkr[g].xy, c4[2*g]);                                           \
        PK(v1, fkr[g].zw, c4[2*g+1]);                                         \
    }                                                                         \
    v2f vt = v0 + v1;                                                         \
    float delta = fb * (fv - (vt.x + vt.y));                                  \
    v2f d2 = {delta, delta};                                                  \
    v2f o0={0.f,0.f}, o1={0.f,0.f};                                           \
    _Pragma("unroll")                                                         \
    for (int g = 0; g < 8; g++) {                                             \
        v4f q = fq4[g];                                                       \
        PK(c4[2*g],   d2, fkr[g].xy); PK(o0, q.xy, c4[2*g]);                  \
        PK(c4[2*g+1], d2, fkr[g].zw); PK(o1, q.zw, c4[2*g+1]);                \
    }                                                                         \
    v2f ot = o0 + o1;                                                         \
    if (lo) Og[((size_t)(T) * NBH + bh) * DD + half] = ot.x + ot.y;           \
}

__global__ __launch_bounds__(64, 1) void srwm_fwm_kernel(
    const float* __restrict__ xg,
    const float* __restrict__ Wy_g, const float* __restrict__ Wq_g,
    const float* __restrict__ Wk_g, const float* __restrict__ wb_g,
    const float* __restrict__ sWy_g, const float* __restrict__ sWq_g,
    const float* __restrict__ sWk_g, const float* __restrict__ swb_g,
    const float* __restrict__ F_g,
    float* __restrict__ Og)
{
    const int bh   = blockIdx.x;
    const int hh   = bh & 7;
    const int lane = threadIdx.x;      // 0..63, one wave
    const int half = lane & 31;
    const bool lo  = lane < 32;

    __shared__ __align__(16) float slab[2][4][DD];  // [parity][qmk,kh,fq,fk]

    v2f c1[16], c2[16], c3[16], c4[16];
    v2f xa[16], xb[16];

    // ---- init c1: Wy column `lane` ----
    {
        const float* wp = Wy_g  + (size_t)hh * DD * YDN + lane;
        const float* sp = sWy_g + (size_t)bh * DD * YDN + lane;
        #pragma unroll
        for (int d = 0; d < 16; d++) {
            v2f t;
            t.x = wp[(2*d)   * YDN] + sp[(2*d)   * YDN];
            t.y = wp[(2*d+1) * YDN] + sp[(2*d+1) * YDN];
            c1[d] = t;
        }
    }
    // ---- init c2: Wy col 64+lane (lanes 0-32) | wb col lane-33 (33-36) ----
    #pragma unroll
    for (int d = 0; d < 16; d++) c2[d] = (v2f){0.f, 0.f};
    if (lane <= 32) {
        const float* wp = Wy_g  + (size_t)hh * DD * YDN + 64 + lane;
        const float* sp = sWy_g + (size_t)bh * DD * YDN + 64 + lane;
        #pragma unroll
        for (int d = 0; d < 16; d++) {
            v2f t;
            t.x = wp[(2*d)   * YDN] + sp[(2*d)   * YDN];
            t.y = wp[(2*d+1) * YDN] + sp[(2*d+1) * YDN];
            c2[d] = t;
        }
    } else if (lane <= 36) {
        const int e = lane - 33;
        const float* wp = wb_g  + (size_t)hh * DD * 4 + e;
        const float* sp = swb_g + (size_t)bh * DD * 4 + e;
        #pragma unroll
        for (int d = 0; d < 16; d++) {
            v2f t;
            t.x = wp[(2*d)   * 4] + sp[(2*d)   * 4];
            t.y = wp[(2*d+1) * 4] + sp[(2*d+1) * 4];
            c2[d] = t;
        }
    }
    // ---- init c3: Wq col (lanes 0-31) / Wk col (lanes 32-63) ----
    {
        const float* wp = (lo ? Wq_g  : Wk_g)  + (size_t)hh * DD * DD + half;
        const float* sp = (lo ? sWq_g : sWk_g) + (size_t)bh * DD * DD + half;
        #pragma unroll
        for (int d = 0; d < 16; d++) {
            v2f t;
            t.x = wp[(2*d)   * DD] + sp[(2*d)   * DD];
            t.y = wp[(2*d+1) * DD] + sp[(2*d+1) * DD];
            c3[d] = t;
        }
    }
    // ---- init c4: F col (lanes 0-31) ----
    #pragma unroll
    for (int d = 0; d < 16; d++) c4[d] = (v2f){0.f, 0.f};
    if (lo) {
        const float* fp = F_g + (size_t)bh * DD * DD + half;
        #pragma unroll
        for (int d = 0; d < 16; d++) {
            v2f t;
            t.x = fp[(2*d)   * DD];
            t.y = fp[(2*d+1) * DD];
            c4[d] = t;
        }
    }

    LOADX(xa, 0)
    LOADX(xb, 1)

    for (int t = 0; t < TT; t += 2) {
        STEP(t,     0, xa)
        STEP(t + 1, 1, xb)
    }
}

// ---------------------------------------------------------------------------
// Kernel 3: out = h + O @ W_out^T   (M=32768, N=K=256), fp32.
// ---------------------------------------------------------------------------
#define GM 128
#define GN 64
#define GK 16

__global__ __launch_bounds__(256, 1) void out_proj_kernel(
    const float* __restrict__ O, const float* __restrict__ W,
    const float* __restrict__ hg, float* __restrict__ outg)
{
    __shared__ float As[GK][GM + 4];
    __shared__ float Bs[GK][GN + 4];
    const int tid = threadIdx.x;
    const int tx  = tid & 15;
    const int ty  = tid >> 4;
    const int r0  = blockIdx.x * GM;
    const int c0  = blockIdx.y * GN;

    float acc[8][4];
    #pragma unroll
    for (int i = 0; i < 8; i++)
        #pragma unroll
        for (int j = 0; j < 4; j++) acc[i][j] = 0.f;

    const int am  = tid >> 1;
    const int akg = (tid & 1) * 8;
    const int bn  = tid >> 2;
    const int bkg = (tid & 3) * 4;

    for (int k0 = 0; k0 < INN; k0 += GK) {
        float4 a0 = *(const float4*)(O + (size_t)(r0 + am) * INN + k0 + akg);
        float4 a1 = *(const float4*)(O + (size_t)(r0 + am) * INN + k0 + akg + 4);
        float4 w0 = *(const float4*)(W + (size_t)(c0 + bn) * INN + k0 + bkg);
        As[akg+0][am] = a0.x; As[akg+1][am] = a0.y; As[akg+2][am] = a0.z; As[akg+3][am] = a0.w;
        As[akg+4][am] = a1.x; As[akg+5][am] = a1.y; As[akg+6][am] = a1.z; As[akg+7][am] = a1.w;
        Bs[bkg+0][bn] = w0.x; Bs[bkg+1][bn] = w0.y;
        Bs[bkg+2][bn] = w0.z; Bs[bkg+3][bn] = w0.w;
        __syncthreads();
        #pragma unroll
        for (int k = 0; k < GK; k++) {
            float4 av0 = *(const float4*)&As[k][ty * 8];
            float4 av1 = *(const float4*)&As[k][ty * 8 + 4];
            float4 bv  = *(const float4*)&Bs[k][tx * 4];
            float a[8] = {av0.x, av0.y, av0.z, av0.w, av1.x, av1.y, av1.z, av1.w};
            float bb[4] = {bv.x, bv.y, bv.z, bv.w};
            #pragma unroll
            for (int i = 0; i < 8; i++)
                #pragma unroll
                for (int j = 0; j < 4; j++) acc[i][j] += a[i] * bb[j];
        }
        __syncthreads();
    }

    #pragma unroll
    for (int i = 0; i < 8; i++) {
        size_t r = (size_t)(r0 + ty * 8 + i);
        float4 hv = *(const float4*)(hg + r * INN + c0 + tx * 4);
        float4 o;
        o.x = hv.x + acc[i][0];
        o.y = hv.y + acc[i][1];
        o.z = hv.z + acc[i][2];
        o.w = hv.w + acc[i][3];
        *(float4*)(outg + r * INN + c0 + tx * 4) = o;
    }
}

// ---------------------------------------------------------------------------
extern "C" void kernel_launch(void* const* d_in, const int* in_sizes, int n_in,
                              void* d_out, int out_size, void* d_ws, size_t ws_size,
                              hipStream_t stream)
{
    (void)in_sizes; (void)n_in; (void)out_size; (void)ws_size;

    const float* hg   = (const float*)d_in[0];
    const float* Wy   = (const float*)d_in[1];
    const float* Wq   = (const float*)d_in[2];
    const float* Wk   = (const float*)d_in[3];
    const float* wb   = (const float*)d_in[4];
    const float* Wout = (const float*)d_in[5];
    const float* sWy  = (const float*)d_in[6];
    const float* sWq  = (const float*)d_in[7];
    const float* sWk  = (const float*)d_in[8];
    const float* swb  = (const float*)d_in[9];
    const float* Fw   = (const float*)d_in[10];
    float* out = (float*)d_out;

    float* xg = (float*)d_ws;                      // (T,B,H,D) fp32
    float* Og = xg + (size_t)TT * BB * INN;        // (T,B,IN)  fp32

    softmax_x_kernel<<<TT * BB * HH / 8, 256, 0, stream>>>(hg, xg);
    srwm_fwm_kernel<<<NBH, 64, 0, stream>>>(xg, Wy, Wq, Wk, wb,
                                            sWy, sWq, sWk, swb, Fw, Og);
    out_proj_kernel<<<dim3(TT * BB / GM, INN / GN), 256, 0, stream>>>(Og, Wout, hg, out);
}

// Round 8
// 1037.385 us; speedup vs baseline: 1.0917x; 1.0917x over previous
//
#include <hip/hip_runtime.h>
#include <cstdint>

#define TT  1024
#define BB  32
#define HH  8
#define DD  32
#define YDN 97
#define INN 256
#define NBH (BB*HH)

typedef float v2f __attribute__((ext_vector_type(2)));
typedef float v4f __attribute__((ext_vector_type(4)));

// packed fp32 FMA (v_pk_fma_f32 on CDNA)
#define PK(acc, a, b) (acc) = __builtin_elementwise_fma((a), (b), (acc))

// LDS-only barrier: drains lgkmcnt, leaves global loads/stores in flight.
__device__ __forceinline__ void bar_lds() {
    asm volatile("s_waitcnt lgkmcnt(0)\n\ts_barrier" ::: "memory");
}

template<int C>
__device__ __forceinline__ float dppf(float x) {
    return __int_as_float(__builtin_amdgcn_update_dpp(
        0, __float_as_int(x), C, 0xF, 0xF, true));
}
__device__ __forceinline__ float swz16(float x) {
    return __int_as_float(__builtin_amdgcn_ds_swizzle(__float_as_int(x), 0x401F));
}
__device__ __forceinline__ float red_max32(float v) {
    v = fmaxf(v, dppf<0xB1>(v));
    v = fmaxf(v, dppf<0x4E>(v));
    v = fmaxf(v, dppf<0x141>(v));
    v = fmaxf(v, dppf<0x140>(v));
    v = fmaxf(v, swz16(v));
    return v;
}
__device__ __forceinline__ float red_sum32(float v) {
    v += dppf<0xB1>(v);
    v += dppf<0x4E>(v);
    v += dppf<0x141>(v);
    v += dppf<0x140>(v);
    v += swz16(v);
    return v;
}
__device__ __forceinline__ float cexp(float v) {
    return __expf(fminf(v, 60.f));
}
__device__ __forceinline__ float sigm(float v) {
    return __builtin_amdgcn_rcpf(1.f + __expf(-v));
}
__device__ __forceinline__ float dot16(const v2f* a, const v2f* b) {
    v2f a0 = {0.f,0.f}, a1 = {0.f,0.f}, a2 = {0.f,0.f}, a3 = {0.f,0.f};
    #pragma unroll
    for (int g = 0; g < 4; g++) {
        PK(a0, a[4*g+0], b[4*g+0]);
        PK(a1, a[4*g+1], b[4*g+1]);
        PK(a2, a[4*g+2], b[4*g+2]);
        PK(a3, a[4*g+3], b[4*g+3]);
    }
    v2f t = (a0 + a1) + (a2 + a3);
    return t.x + t.y;
}
__device__ __forceinline__ float sum16(const v2f* a) {
    v2f s0 = a[0]+a[1],   s1 = a[2]+a[3],   s2 = a[4]+a[5],   s3 = a[6]+a[7];
    v2f s4 = a[8]+a[9],   s5 = a[10]+a[11], s6 = a[12]+a[13], s7 = a[14]+a[15];
    v2f u  = ((s0+s1)+(s2+s3)) + ((s4+s5)+(s6+s7));
    return u.x + u.y;
}

// ---------------------------------------------------------------------------
// Kernel 1: x = softmax(h) over last dim (rows of 32)
// ---------------------------------------------------------------------------
__global__ __launch_bounds__(256, 1) void softmax_x_kernel(
    const float* __restrict__ hg, float* __restrict__ xg)
{
    const int row  = blockIdx.x * 8 + (threadIdx.x >> 5);
    const int lane = threadIdx.x & 31;
    float v = hg[(size_t)row * DD + lane];
    float m = red_max32(v);
    float ex = __expf(v - m);
    float sm = red_sum32(ex);
    xg[(size_t)row * DD + lane] = ex * __builtin_amdgcn_rcpf(sm);
}

// ---------------------------------------------------------------------------
// Kernel 2: SRWM + fast-weight memory. One block (4 waves) per (b,h).
// COLUMN layout: each lane owns one column M[:,e] of one state matrix.
//   w0: Wy cols 0-63 (produce exp(y[0:64]) = fq/fk exps)
//   w1: Wy cols 64-96 (lanes 0-32; lane31.. fv raw, lane32 fb) + wb cols (33-36)
//   w2: Wq cols (lanes 0-31) / Wk cols (lanes 32-63)
//   w3: F cols (fast-weight memory consumer; no x, no publishes)
// ONE barrier/step. Producers publish RAW exps pre-barrier; consumers gather
// vectors post-barrier and compute softmax sums LOCALLY (register tree) —
// no cross-lane reductions and no second LDS trip on the serial chain.
// Exact algebra: pre(t+1) = x(t+1)·row(t-1) + bs·rk·(x(t+1)·ek(t)).
// ---------------------------------------------------------------------------

#define LOADX(dst, t) {                                                       \
    int tc_ = (t); if (tc_ > TT-1) tc_ = TT-1;                                \
    const v4f* p_ = (const v4f*)(xg + ((size_t)tc_ * NBH + bh) * DD);         \
    _Pragma("unroll")                                                         \
    for (int g_ = 0; g_ < 8; g_++) {                                          \
        v4f v_ = p_[g_]; dst[2*g_] = v_.xy; dst[2*g_+1] = v_.zw;              \
    }                                                                         \
}

#define RDV(dst, src) {                                                       \
    const v4f* p_ = (const v4f*)(src);                                        \
    _Pragma("unroll")                                                         \
    for (int g_ = 0; g_ < 8; g_++) {                                          \
        v4f v_ = p_[g_]; dst[2*g_] = v_.xy; dst[2*g_+1] = v_.zw;              \
    }                                                                         \
}

// publish pre(t+1)-derived values into buffer PN
#define PUB(PRE, PN) {                                                        \
    if (wv == 0) {                                                            \
        EYs[PN][lane] = cexp(PRE);                                            \
    } else if (wv == 1) {                                                     \
        if (lane < 32)       FVs[PN][lane] = (PRE);                           \
        else if (lane == 32) FBs[PN] = sigm(PRE);                             \
        else if (lane <= 36) BETA[PN][lane - 33] = sigm(PRE);                 \
    } else {                                                                  \
        if (lane < 32) EQs[PN][lane] = cexp(PRE);                             \
        else           EKs[PN][half] = cexp(PRE);                             \
    }                                                                         \
}

#define REGION(T, XCUR, XNXT) {                                               \
    const int P_ = (T) & 1, Pn_ = ((T) + 1) & 1;                              \
    if (wv != 3) {                                                            \
        v2f eqv[16], ekv[16];                                                 \
        RDV(eqv, EQs[P_])                                                     \
        RDV(ekv, EKs[P_])                                                     \
        float beta = BETA[P_][bidx];                                          \
        float Sq = sum16(eqv), Sk = sum16(ekv);                               \
        float dq = dot16(eqv, col);                                           \
        float dk = dot16(ekv, col);                                           \
        float c  = dot16(XCUR, ekv);                                          \
        float rq = __builtin_amdgcn_rcpf(Sq);                                 \
        float rk = __builtin_amdgcn_rcpf(Sk);                                 \
        float bs  = beta * (rq * dq - rk * dk);                               \
        float brk = bs * rk;                                                  \
        float pre = preO + brk * c;                                           \
        PUB(pre, Pn_)                                                         \
        v2f brk2 = {brk, brk};                                                \
        _Pragma("unroll")                                                     \
        for (int g_ = 0; g_ < 16; g_++) PK(col[g_], brk2, ekv[g_]);           \
        preO = dot16(XNXT, col);                                              \
        LOADX(XCUR, (T) + 3)                                                  \
    } else {                                                                  \
        v2f eyq[16], eyk[16];                                                 \
        RDV(eyq, EYs[P_])                                                     \
        RDV(eyk, (EYs[P_] + 32))                                              \
        float fv = FVs[P_][half];                                             \
        float fb = FBs[P_];                                                   \
        float Sfq = sum16(eyq), Sfk = sum16(eyk);                             \
        float rfk = __builtin_amdgcn_rcpf(Sfk);                               \
        float vold = rfk * dot16(eyk, col);                                   \
        float delta = fb * (fv - vold);                                       \
        float drk = delta * rfk;                                              \
        v2f d2_ = {drk, drk};                                                 \
        v2f o0_ = {0.f,0.f}, o1_ = {0.f,0.f};                                 \
        _Pragma("unroll")                                                     \
        for (int g_ = 0; g_ < 8; g_++) {                                      \
            PK(col[2*g_],   d2_, eyk[2*g_]);                                  \
            PK(o0_, eyq[2*g_],   col[2*g_]);                                  \
            PK(col[2*g_+1], d2_, eyk[2*g_+1]);                                \
            PK(o1_, eyq[2*g_+1], col[2*g_+1]);                                \
        }                                                                     \
        v2f ot_ = o0_ + o1_;                                                  \
        float outv = __builtin_amdgcn_rcpf(Sfq) * (ot_.x + ot_.y);            \
        if (lane < 32)                                                        \
            Og[((size_t)(T) * NBH + bh) * DD + half] = outv;                  \
    }                                                                         \
    bar_lds();                                                                \
}

__global__ __launch_bounds__(256, 1) void srwm_fwm_kernel(
    const float* __restrict__ xg,
    const float* __restrict__ Wy_g, const float* __restrict__ Wq_g,
    const float* __restrict__ Wk_g, const float* __restrict__ wb_g,
    const float* __restrict__ sWy_g, const float* __restrict__ sWq_g,
    const float* __restrict__ sWk_g, const float* __restrict__ swb_g,
    const float* __restrict__ F_g,
    float* __restrict__ Og)
{
    const int bh   = blockIdx.x;
    const int hh   = bh & 7;
    const int tid  = threadIdx.x;
    const int wv   = tid >> 6;
    const int lane = tid & 63;
    const int half = lane & 31;

    __shared__ __align__(16) float EQs[2][DD];
    __shared__ __align__(16) float EKs[2][DD];
    __shared__ __align__(16) float EYs[2][64];
    __shared__ __align__(16) float FVs[2][DD];
    __shared__ __align__(16) float BETA[2][4];
    __shared__ float FBs[2];

    v2f col[16];            // this lane's state column
    v2f xa[16], xb[16];     // x(t+1), x(t+2) ring (waves 0-2)
    float preO = 0.f;

    int bidx = 0;
    if (wv == 1)      bidx = (lane <= 32) ? 0 : 3;
    else if (wv == 2) bidx = (lane < 32) ? 1 : 2;

    // ---- init column registers ----
    #pragma unroll
    for (int d = 0; d < 16; d++) col[d] = (v2f){0.f, 0.f};
    if (wv == 0) {
        const float* wp = Wy_g  + (size_t)hh * DD * YDN + lane;
        const float* sp = sWy_g + (size_t)bh * DD * YDN + lane;
        #pragma unroll
        for (int d = 0; d < 16; d++) {
            v2f t;
            t.x = wp[(2*d)   * YDN] + sp[(2*d)   * YDN];
            t.y = wp[(2*d+1) * YDN] + sp[(2*d+1) * YDN];
            col[d] = t;
        }
    } else if (wv == 1) {
        if (lane <= 32) {
            const float* wp = Wy_g  + (size_t)hh * DD * YDN + 64 + lane;
            const float* sp = sWy_g + (size_t)bh * DD * YDN + 64 + lane;
            #pragma unroll
            for (int d = 0; d < 16; d++) {
                v2f t;
                t.x = wp[(2*d)   * YDN] + sp[(2*d)   * YDN];
                t.y = wp[(2*d+1) * YDN] + sp[(2*d+1) * YDN];
                col[d] = t;
            }
        } else if (lane <= 36) {
            const int e = lane - 33;
            const float* wp = wb_g  + (size_t)hh * DD * 4 + e;
            const float* sp = swb_g + (size_t)bh * DD * 4 + e;
            #pragma unroll
            for (int d = 0; d < 16; d++) {
                v2f t;
                t.x = wp[(2*d)   * 4] + sp[(2*d)   * 4];
                t.y = wp[(2*d+1) * 4] + sp[(2*d+1) * 4];
                col[d] = t;
            }
        }
    } else if (wv == 2) {
        const float* wp = (lane < 32 ? Wq_g  : Wk_g)  + (size_t)hh * DD * DD + half;
        const float* sp = (lane < 32 ? sWq_g : sWk_g) + (size_t)bh * DD * DD + half;
        #pragma unroll
        for (int d = 0; d < 16; d++) {
            v2f t;
            t.x = wp[(2*d)   * DD] + sp[(2*d)   * DD];
            t.y = wp[(2*d+1) * DD] + sp[(2*d+1) * DD];
            col[d] = t;
        }
    } else {
        if (lane < 32) {
            const float* fp = F_g + (size_t)bh * DD * DD + half;
            #pragma unroll
            for (int d = 0; d < 16; d++) {
                v2f t;
                t.x = fp[(2*d)   * DD];
                t.y = fp[(2*d+1) * DD];
                col[d] = t;
            }
        }
    }

    // ---- prologue: step-0 publication + preO(1) + x ring prefill ----
    if (wv != 3) {
        v2f x0t[16];
        LOADX(x0t, 0)
        float pre0 = dot16(x0t, col);
        PUB(pre0, 0)
        LOADX(xa, 1)
        LOADX(xb, 2)
        preO = dot16(xa, col);
    }
    bar_lds();

    // ---- main loop: one barrier per step ----
    for (int t = 0; t < TT; t += 2) {
        REGION(t,     xa, xb)
        REGION(t + 1, xb, xa)
    }
}

// ---------------------------------------------------------------------------
// Kernel 3: out = h + O @ W_out^T   (M=32768, N=K=256), fp32.
// ---------------------------------------------------------------------------
#define GM 128
#define GN 64
#define GK 16

__global__ __launch_bounds__(256, 1) void out_proj_kernel(
    const float* __restrict__ O, const float* __restrict__ W,
    const float* __restrict__ hg, float* __restrict__ outg)
{
    __shared__ float As[GK][GM + 4];
    __shared__ float Bs[GK][GN + 4];
    const int tid = threadIdx.x;
    const int tx  = tid & 15;
    const int ty  = tid >> 4;
    const int r0  = blockIdx.x * GM;
    const int c0  = blockIdx.y * GN;

    float acc[8][4];
    #pragma unroll
    for (int i = 0; i < 8; i++)
        #pragma unroll
        for (int j = 0; j < 4; j++) acc[i][j] = 0.f;

    const int am  = tid >> 1;
    const int akg = (tid & 1) * 8;
    const int bn  = tid >> 2;
    const int bkg = (tid & 3) * 4;

    for (int k0 = 0; k0 < INN; k0 += GK) {
        float4 a0 = *(const float4*)(O + (size_t)(r0 + am) * INN + k0 + akg);
        float4 a1 = *(const float4*)(O + (size_t)(r0 + am) * INN + k0 + akg + 4);
        float4 w0 = *(const float4*)(W + (size_t)(c0 + bn) * INN + k0 + bkg);
        As[akg+0][am] = a0.x; As[akg+1][am] = a0.y; As[akg+2][am] = a0.z; As[akg+3][am] = a0.w;
        As[akg+4][am] = a1.x; As[akg+5][am] = a1.y; As[akg+6][am] = a1.z; As[akg+7][am] = a1.w;
        Bs[bkg+0][bn] = w0.x; Bs[bkg+1][bn] = w0.y;
        Bs[bkg+2][bn] = w0.z; Bs[bkg+3][bn] = w0.w;
        __syncthreads();
        #pragma unroll
        for (int k = 0; k < GK; k++) {
            float4 av0 = *(const float4*)&As[k][ty * 8];
            float4 av1 = *(const float4*)&As[k][ty * 8 + 4];
            float4 bv  = *(const float4*)&Bs[k][tx * 4];
            float a[8] = {av0.x, av0.y, av0.z, av0.w, av1.x, av1.y, av1.z, av1.w};
            float bb[4] = {bv.x, bv.y, bv.z, bv.w};
            #pragma unroll
            for (int i = 0; i < 8; i++)
                #pragma unroll
                for (int j = 0; j < 4; j++) acc[i][j] += a[i] * bb[j];
        }
        __syncthreads();
    }

    #pragma unroll
    for (int i = 0; i < 8; i++) {
        size_t r = (size_t)(r0 + ty * 8 + i);
        float4 hv = *(const float4*)(hg + r * INN + c0 + tx * 4);
        float4 o;
        o.x = hv.x + acc[i][0];
        o.y = hv.y + acc[i][1];
        o.z = hv.z + acc[i][2];
        o.w = hv.w + acc[i][3];
        *(float4*)(outg + r * INN + c0 + tx * 4) = o;
    }
}

// ---------------------------------------------------------------------------
extern "C" void kernel_launch(void* const* d_in, const int* in_sizes, int n_in,
                              void* d_out, int out_size, void* d_ws, size_t ws_size,
                              hipStream_t stream)
{
    (void)in_sizes; (void)n_in; (void)out_size; (void)ws_size;

    const float* hg   = (const float*)d_in[0];
    const float* Wy   = (const float*)d_in[1];
    const float* Wq   = (const float*)d_in[2];
    const float* Wk   = (const float*)d_in[3];
    const float* wb   = (const float*)d_in[4];
    const float* Wout = (const float*)d_in[5];
    const float* sWy  = (const float*)d_in[6];
    const float* sWq  = (const float*)d_in[7];
    const float* sWk  = (const float*)d_in[8];
    const float* swb  = (const float*)d_in[9];
    const float* Fw   = (const float*)d_in[10];
    float* out = (float*)d_out;

    float* xg = (float*)d_ws;                      // (T,B,H,D) fp32
    float* Og = xg + (size_t)TT * BB * INN;        // (T,B,IN)  fp32

    softmax_x_kernel<<<TT * BB * HH / 8, 256, 0, stream>>>(hg, xg);
    srwm_fwm_kernel<<<NBH, 256, 0, stream>>>(xg, Wy, Wq, Wk, wb,
                                             sWy, sWq, sWk, swb, Fw, Og);
    out_proj_kernel<<<dim3(TT * BB / GM, INN / GN), 256, 0, stream>>>(Og, Wout, hg, out);
}